// Round 7
// baseline (982.674 us; speedup 1.0000x reference)
//
#include <hip/hip_runtime.h>

typedef __attribute__((ext_vector_type(8))) short short8v;
typedef __attribute__((ext_vector_type(4))) float f32x4;

typedef const __attribute__((address_space(1))) void gvoid_t;
typedef __attribute__((address_space(3))) void svoid_t;

__device__ __forceinline__ unsigned short f2b(float f) {
    unsigned u = __float_as_uint(f);
    unsigned r = (u + 0x7fffu + ((u >> 16) & 1u)) >> 16;
    return (unsigned short)r;
}
__device__ __forceinline__ float b2f(unsigned short h) {
    return __uint_as_float((unsigned)h << 16);
}

// ---------------- elementwise / setup kernels ----------------

// X = dt*A = scale * sigmoid(alpha_i) * (adj - I)  -> f32 + bf16
__global__ void k_build_A(const float* __restrict__ adj,
                          const float* __restrict__ alpha,
                          float* __restrict__ Xs, unsigned short* __restrict__ Xb,
                          int n, float scale)
{
    int j = blockIdx.x * 256 + threadIdx.x;
    int i = blockIdx.y;
    if (j >= n) return;
    size_t idx = (size_t)i * n + j;
    float s = 1.f / (1.f + expf(-alpha[i]));
    float v = scale * s * (adj[idx] - (i == j ? 1.f : 0.f));
    Xs[idx] = v;
    Xb[idx] = f2b(v);
}

// E = w - I (bf16), Ed = E*diag(clip(d)) (bf16 + f32)
__global__ void k_build_EW(const float* __restrict__ w,
                           const float* __restrict__ d,
                           unsigned short* __restrict__ Eb,
                           unsigned short* __restrict__ Edb,
                           float* __restrict__ Edf, int h)
{
    int j = blockIdx.x * 256 + threadIdx.x;
    int i = blockIdx.y;
    if (j >= h) return;
    size_t idx = (size_t)i * h + j;
    float e = w[idx] - (i == j ? 1.f : 0.f);
    float dc = fminf(fmaxf(d[j], 0.f), 1.f);
    Eb[idx] = f2b(e);
    float ed = e * dc;
    Edb[idx] = f2b(ed);
    Edf[idx] = ed;
}

// R = dt * ( diag(clip(d)-1) + Ed + Ed^T )
__global__ void k_build_R(const float* __restrict__ Ed,
                          const float* __restrict__ d,
                          float* __restrict__ R, int h, float dt)
{
    __shared__ float tile[32][33];
    int bx = blockIdx.x * 32, by = blockIdx.y * 32;
    int tx = threadIdx.x, ty = threadIdx.y;
    #pragma unroll
    for (int r = 0; r < 32; r += 8)
        tile[ty + r][tx] = Ed[(size_t)(bx + ty + r) * h + by + tx];
    __syncthreads();
    #pragma unroll
    for (int r = 0; r < 32; r += 8) {
        int i = by + ty + r, j = bx + tx;
        float v = Ed[(size_t)i * h + j] + tile[tx][ty + r];
        if (i == j) v += fminf(fmaxf(d[i], 0.f), 1.f) - 1.f;
        R[(size_t)i * h + j] = dt * v;
    }
}

// transpose: in[R][C] f32 -> out[C][R] bf16
__global__ void k_tsplit(const float* __restrict__ in,
                         unsigned short* __restrict__ outT, int R, int C)
{
    __shared__ float tile[32][33];
    int bx = blockIdx.x * 32, by = blockIdx.y * 32;
    int tx = threadIdx.x, ty = threadIdx.y;
    #pragma unroll
    for (int r = 0; r < 32; r += 8)
        tile[ty + r][tx] = in[(size_t)(by + ty + r) * C + bx + tx];
    __syncthreads();
    #pragma unroll
    for (int r = 0; r < 32; r += 8)
        outT[(size_t)(bx + ty + r) * R + by + tx] = f2b(tile[tx][ty + r]);
}

// ------- bf16 MFMA GEMM: BK=32, 4-buffer depth-2 single-barrier pipeline -------
// acc = A @ B  (A: MxK bf16 row-major; BT: NxK bf16 row-major = B transposed)
// v  = alpha*acc + beta*D + g2*D2 + g3*b2f(Db) -> C (f32), Cb (bf16), CbT ([N][M] bf16)
// v2 = pa*acc + pb*D + pc*b2f(Db)              -> Cb2 (bf16)
// v3 = qa*acc + qb*D + qc*b2f(Db)              -> Cb3 (bf16)
// 256 threads = 4 waves (2x2); per-wave (FM*16)x(FN*16). BM=FM*32, BN=FN*32.
// LDS tiles stored CHUNK-MAJOR: [k4][row][16B] -> frag ds_read_b128 is 16
// contiguous lanes x 16B = conflict-free, no swizzle needed; global_load_lds
// dest stays linear (rule #21 satisfied trivially).
// K-loop: {stage(t+2); s_waitcnt vmcnt(2*LPT); s_barrier; ds_read; MFMA} —
// one barrier/step; 4-buffer recycle distance makes overwrite races impossible.
// SWZ: XCD row-stripe swizzle (q=bid&7 owns 2 row-blocks x all cols) so the
// A-panel (operator) is L2-resident per XCD. Requires gridDim.y==16, nb%8==0.

template<int FM, int FN, bool SWZ>
__global__ __launch_bounds__(256, 2)
void gemm_bf16(const unsigned short* __restrict__ A,
               const unsigned short* __restrict__ BT,
               float* __restrict__ C,
               unsigned short* __restrict__ Cb,
               unsigned short* __restrict__ Cb2,
               unsigned short* __restrict__ Cb3,
               unsigned short* __restrict__ CbT,
               const float* __restrict__ D,
               const float* __restrict__ D2,
               const unsigned short* __restrict__ Db,
               int M, int N, int K,
               float alpha, float beta, float g2, float g3,
               float pa, float pb, float pc,
               float qa, float qb, float qc)
{
    constexpr int BM = FM * 32, BN = FN * 32, BK = 32;
    constexpr int ACH = BM * 4;          // 16B chunks per A tile
    constexpr int BCH = BN * 4;
    constexpr int AIT = ACH / 256;
    constexpr int BIT = BCH / 256;
    constexpr int LPT = AIT + BIT;       // loads in flight per staged tile
    __shared__ unsigned short As[4][BM * BK];
    __shared__ unsigned short Bs[4][BN * BK];

    int bx = blockIdx.x, by = blockIdx.y;
    if (SWZ) {   // row-stripe per XCD: q owns rows {2q, 2q+1} x all cols
        int bid = by * gridDim.x + bx;
        int q = bid & 7, c = bid >> 3;
        by = q * 2 + (c & 1);
        bx = c >> 1;
    }

    const int tid  = threadIdx.x;
    const int lane = tid & 63;
    const int wave = tid >> 6;
    const int wr = wave >> 1, wc = wave & 1;   // 2 x 2 wave grid
    const int l16 = lane & 15, l4 = lane >> 4;
    const int brow = by * BM, bcol = bx * BN;

    f32x4 acc[FM][FN];
    #pragma unroll
    for (int m = 0; m < FM; ++m)
        #pragma unroll
        for (int j = 0; j < FN; ++j)
            acc[m][j] = (f32x4){0.f, 0.f, 0.f, 0.f};

    const unsigned short* Ab = A + (size_t)brow * K;
    const unsigned short* Bb = BT + (size_t)bcol * K;
    const int nt = K / BK;

    auto stage = [&](int b, int k0) {
        #pragma unroll
        for (int it = 0; it < AIT; ++it) {
            int cb = it * 256 + wave * 64;          // wave-uniform chunk base
            int ch = cb + lane;
            int r = ch % BM, k4 = ch / BM;          // chunk-major dest layout
            __builtin_amdgcn_global_load_lds(
                (gvoid_t*)(Ab + (size_t)r * K + k0 + k4 * 8),
                (svoid_t*)(&As[b][cb * 8]), 16, 0, 0);
        }
        #pragma unroll
        for (int it = 0; it < BIT; ++it) {
            int cb = it * 256 + wave * 64;
            int ch = cb + lane;
            int r = ch % BN, k4 = ch / BN;
            __builtin_amdgcn_global_load_lds(
                (gvoid_t*)(Bb + (size_t)r * K + k0 + k4 * 8),
                (svoid_t*)(&Bs[b][cb * 8]), 16, 0, 0);
        }
    };

    stage(0, 0);
    stage(1, BK);

    for (int t = 0; t < nt; ++t) {
        const int cur = t & 3;
        if (t + 2 < nt) stage((t + 2) & 3, (t + 2) * BK);

        const int rem = nt - 1 - t;
        if (rem >= 2)      asm volatile("s_waitcnt vmcnt(%0)" :: "i"(2 * LPT) : "memory");
        else if (rem == 1) asm volatile("s_waitcnt vmcnt(%0)" :: "i"(LPT) : "memory");
        else               asm volatile("s_waitcnt vmcnt(0)" ::: "memory");
        __builtin_amdgcn_s_barrier();
        asm volatile("" ::: "memory");
        __builtin_amdgcn_sched_barrier(0);

        short8v af[FM], bf[FN];
        #pragma unroll
        for (int m = 0; m < FM; ++m) {
            int r = wr * FM * 16 + m * 16 + l16;
            af[m] = *(const short8v*)&As[cur][(l4 * BM + r) * 8];
        }
        #pragma unroll
        for (int j = 0; j < FN; ++j) {
            int r = wc * FN * 16 + j * 16 + l16;
            bf[j] = *(const short8v*)&Bs[cur][(l4 * BN + r) * 8];
        }
        __builtin_amdgcn_s_setprio(1);
        #pragma unroll
        for (int m = 0; m < FM; ++m)
            #pragma unroll
            for (int j = 0; j < FN; ++j)
                acc[m][j] = __builtin_amdgcn_mfma_f32_16x16x32_bf16(
                    af[m], bf[j], acc[m][j], 0, 0, 0);
        __builtin_amdgcn_s_setprio(0);
        __builtin_amdgcn_sched_barrier(0);
    }

    #pragma unroll
    for (int m = 0; m < FM; ++m) {
        #pragma unroll
        for (int j = 0; j < FN; ++j) {
            const int row0 = brow + wr * FM * 16 + m * 16 + l4 * 4;
            const int col  = bcol + wc * FN * 16 + j * 16 + l16;
            float vv[4];
            #pragma unroll
            for (int q = 0; q < 4; ++q) {
                size_t idx = (size_t)(row0 + q) * N + col;
                float a0 = acc[m][j][q];
                float v = alpha * a0;
                float dv = 0.f, dbv = 0.f;
                if (D)  { dv = D[idx]; v = fmaf(beta, dv, v); }
                if (D2) v = fmaf(g2, D2[idx], v);
                if (Db) { dbv = b2f(Db[idx]); v = fmaf(g3, dbv, v); }
                vv[q] = v;
                if (C)  C[idx] = v;
                if (Cb) Cb[idx] = f2b(v);
                if (Cb2) {
                    float v2 = pa * a0;
                    if (D)  v2 = fmaf(pb, dv, v2);
                    if (Db) v2 = fmaf(pc, dbv, v2);
                    Cb2[idx] = f2b(v2);
                }
                if (Cb3) {
                    float v3 = qa * a0;
                    if (D)  v3 = fmaf(qb, dv, v3);
                    if (Db) v3 = fmaf(qc, dbv, v3);
                    Cb3[idx] = f2b(v3);
                }
            }
            if (CbT) {
                ushort4 t4;
                t4.x = f2b(vv[0]); t4.y = f2b(vv[1]);
                t4.z = f2b(vv[2]); t4.w = f2b(vv[3]);
                *reinterpret_cast<ushort4*>(&CbT[(size_t)col * M + row0]) = t4;
            }
        }
    }
}

// ---------------- host orchestration ----------------

extern "C" void kernel_launch(void* const* d_in, const int* in_sizes, int n_in,
                              void* d_out, int out_size, void* d_ws, size_t ws_size,
                              hipStream_t stream)
{
    const float* x     = (const float*)d_in[0];   // [n, h]
    const float* x0    = (const float*)d_in[1];   // [n, h]
    const float* adj   = (const float*)d_in[2];   // [n, n]
    const float* alpha = (const float*)d_in[3];   // [n]
    const float* w     = (const float*)d_in[4];   // [h, h]
    const float* dvec  = (const float*)d_in[5];   // [h]

    const int n = in_sizes[3];      // 2048
    const int h = in_sizes[5];      // 1024
    const size_t MB = 1u << 20;
    char* ws = (char*)d_ws;

    typedef unsigned short u16;
    // ---- workspace (MiB offsets, phase-overlaid; peak 106 MiB) ----
    float* Xs    = (float*)(ws + 0 * MB);    // 16  phase A (dies after A2)
    float* tf    = (float*)(ws + 0 * MB);    // 8   scan
    float* za    = (float*)(ws + 8 * MB);    // 8   scan
    u16*   XAb   = (u16*)(ws + 16 * MB);     // 8   dies after A1
    u16*   Eb_   = (u16*)(ws + 16 * MB);     // 2   phase B
    u16*   Edb   = (u16*)(ws + 18 * MB);     // 2
    float* Edf   = (float*)(ws + 20 * MB);   // 4
    u16*   XAT   = (u16*)(ws + 24 * MB);     // 8   dies after A2
    float* R     = (float*)(ws + 24 * MB);   // 4   phase B
    float* XBf   = (float*)(ws + 28 * MB);   // 4
    u16*   T2b   = (u16*)(ws + 32 * MB);     // 8   dies after A2
    u16*   XBb   = (u16*)(ws + 32 * MB);     // 2   phase B
    u16*   XBT   = (u16*)(ws + 34 * MB);     // 2
    u16*   t2b   = (u16*)(ws + 36 * MB);     // 2
    u16*   t3b   = (u16*)(ws + 38 * MB);     // 2
    u16*   Mah   = (u16*)(ws + 40 * MB);     // 8   persists (single step)
    u16*   Pmb   = (u16*)(ws + 48 * MB);     // 8   dies after F
    u16*   tb16  = (u16*)(ws + 48 * MB);     // 4   scan
    u16*   zt    = (u16*)(ws + 52 * MB);     // 4   scan
    u16*   M2ah  = (u16*)(ws + 56 * MB);     // 8   persists (dbl steps)
    float* S3    = (float*)(ws + 64 * MB);   // 4   phase B
    u16*   x0T   = (u16*)(ws + 64 * MB);     // 4   phase C pre (S3 dead)
    u16*   MbT   = (u16*)(ws + 68 * MB);     // 2   persists
    u16*   Mbb   = (u16*)(ws + 70 * MB);     // 2   dies after B5
    u16*   FTb   = (u16*)(ws + 72 * MB);     // 4   dies after u-gemm
    u16*   M2bTb = (u16*)(ws + 76 * MB);     // 2   persists (dbl steps)
    float* Ff    = (float*)(ws + 78 * MB);   // 8   persists
    float* uf    = (float*)(ws + 86 * MB);   // 8   dies after F2
    u16*   ub    = (u16*)(ws + 94 * MB);     // 4   dies after F2
    float* F2f   = (float*)(ws + 98 * MB);   // 8   persists (dbl steps)

    const dim3 blk(256);
    const dim3 g1616(16, 16);
    const dim3 g816(8, 16);
    const float dt = 0.1f;
    const u16* nu16 = nullptr;
    const float* nf32 = nullptr;

    // ===== Phase A: Mah=bf16(e^X-I), Pmb=bf16(phi1-I), M2ah=bf16(e^{2X}-I) =====
    k_build_A<<<dim3(n / 256, n), blk, 0, stream>>>(adj, alpha, Xs, XAb, n, 0.5f * dt);
    k_tsplit<<<dim3(n / 32, n / 32), dim3(32, 8), 0, stream>>>(Xs, XAT, n, n);
    // A1: T2b = bf16(X^2)
    gemm_bf16<4, 4, true><<<g1616, blk, 0, stream>>>(
        XAb, XAT, nullptr, T2b, nullptr, nullptr, nullptr, nf32, nf32, nu16,
        n, n, n, 1.f, 0.f, 0.f, 0.f, 0.f, 0.f, 0.f, 0.f, 0.f, 0.f);
    // A2: acc = X^2@X = X^3
    //   Ma  = X + X^2/2 + X^3/6        -> Mah  (alpha=1/6, D=Xs b=1, Db=T2b g3=1/2)
    //   Pm  = X/2 + X^2/6 + X^3/24     -> Pmb  (pa=1/24, pb=1/2, pc=1/6)
    //   M2a = 2X + 2X^2 + (4/3)X^3     -> M2ah (qa=4/3, qb=2, qc=2)
    gemm_bf16<4, 4, true><<<g1616, blk, 0, stream>>>(
        T2b, XAT, nullptr, Mah, Pmb, M2ah, nullptr, Xs, nf32, T2b,
        n, n, n, 1.f / 6.f, 1.f, 0.f, 0.5f,
        1.f / 24.f, 0.5f, 1.f / 6.f, 4.f / 3.f, 2.f, 2.f);

    // ===== Phase B: Mb = e^{dtB}-I (order 4), M2bT = (Mb^2+2Mb)^T =====
    k_build_EW<<<dim3(h / 256, h), blk, 0, stream>>>(w, dvec, Eb_, Edb, Edf, h);
    k_build_R<<<dim3(h / 32, h / 32), dim3(32, 8), 0, stream>>>(Edf, dvec, R, h, dt);
    // B1: XB = dt*(Ed @ E^T) + R
    gemm_bf16<2, 2, true><<<g1616, blk, 0, stream>>>(
        Edb, Eb_, XBf, XBb, nullptr, nullptr, XBT, R, nf32, nu16,
        h, h, h, dt, 1.f, 0.f, 0.f, 0.f, 0.f, 0.f, 0.f, 0.f, 0.f);
    // B2: t2b = bf16(XB^2/2)
    gemm_bf16<2, 2, true><<<g1616, blk, 0, stream>>>(
        XBb, XBT, nullptr, t2b, nullptr, nullptr, nullptr, nf32, nf32, nu16,
        h, h, h, 0.5f, 0.f, 0.f, 0.f, 0.f, 0.f, 0.f, 0.f, 0.f, 0.f);
    // B3: acc = t2@XB = XB^3/2 ; S3 = acc/3 + XBf + t2 ; t3b = bf16(acc/3)
    gemm_bf16<2, 2, true><<<g1616, blk, 0, stream>>>(
        t2b, XBT, S3, nullptr, t3b, nullptr, nullptr, XBf, nf32, t2b,
        h, h, h, 1.f / 3.f, 1.f, 0.f, 1.f, 1.f / 3.f, 0.f, 0.f, 0.f, 0.f, 0.f);
    // B4: Mb = acc/4 + S3 -> MbT (CbT) + Mbb (Cb)
    gemm_bf16<2, 2, true><<<g1616, blk, 0, stream>>>(
        t3b, XBT, nullptr, Mbb, nullptr, nullptr, MbT, S3, nf32, nu16,
        h, h, h, 0.25f, 1.f, 0.f, 0.f, 0.f, 0.f, 0.f, 0.f, 0.f, 0.f);
    // B5: M2b^T = (Mb^T)^2 + 2 Mb^T  (A=MbT, B=Mb^T so BT=Mbb)
    gemm_bf16<2, 2, true><<<g1616, blk, 0, stream>>>(
        MbT, Mbb, nullptr, M2bTb, nullptr, nullptr, nullptr, nf32, nf32, MbT,
        h, h, h, 1.f, 0.f, 0.f, 2.f, 0.f, 0.f, 0.f, 0.f, 0.f, 0.f);

    // ===== Phase C: forcing chain =====
    k_tsplit<<<dim3(h / 32, n / 32), dim3(32, 8), 0, stream>>>(x0, x0T, n, h);
    // F = dt*(Pm@x0) + dt*x0 -> Ff + FTb
    gemm_bf16<4, 4, true><<<g816, blk, 0, stream>>>(
        Pmb, x0T, Ff, nullptr, nullptr, nullptr, FTb, x0, nf32, nu16,
        n, h, n, dt, dt, 0.f, 0.f, 0.f, 0.f, 0.f, 0.f, 0.f, 0.f);
    // u = Ma@F + F -> uf + ub
    gemm_bf16<4, 4, true><<<g816, blk, 0, stream>>>(
        Mah, FTb, uf, ub, nullptr, nullptr, nullptr, Ff, nf32, nu16,
        n, h, n, 1.f, 1.f, 0.f, 0.f, 0.f, 0.f, 0.f, 0.f, 0.f, 0.f);
    // F2 = u@Mb + u + F
    gemm_bf16<4, 4, true><<<g816, blk, 0, stream>>>(
        ub, MbT, F2f, nullptr, nullptr, nullptr, nullptr, uf, Ff, nu16,
        n, h, h, 1.f, 1.f, 1.f, 0.f, 0.f, 0.f, 0.f, 0.f, 0.f, 0.f);

    // ===== scan: 4 double-steps + 1 single step (total 9 = int(1.0//0.1)) =====
    k_tsplit<<<dim3(h / 32, n / 32), dim3(32, 8), 0, stream>>>(x, zt, n, h);
    const float* zf = x;
    for (int s = 0; s < 4; ++s) {
        // G1: tf = M2a@z + z ; tb16 = bf16(tf)
        gemm_bf16<4, 4, true><<<g816, blk, 0, stream>>>(
            M2ah, zt, tf, tb16, nullptr, nullptr, nullptr, zf, nf32, nu16,
            n, h, n, 1.f, 1.f, 0.f, 0.f, 0.f, 0.f, 0.f, 0.f, 0.f, 0.f);
        // G2: z'' = t@M2b + t + F2 -> za (f32) + zt (bf16 transposed)
        gemm_bf16<4, 4, true><<<g816, blk, 0, stream>>>(
            tb16, M2bTb, za, nullptr, nullptr, nullptr, zt, tf, F2f, nu16,
            n, h, h, 1.f, 1.f, 1.f, 0.f, 0.f, 0.f, 0.f, 0.f, 0.f, 0.f);
        zf = za;
    }
    // single step: tf = Ma@z + z ; out = t@Mb + t + F
    gemm_bf16<4, 4, true><<<g816, blk, 0, stream>>>(
        Mah, zt, tf, tb16, nullptr, nullptr, nullptr, za, nf32, nu16,
        n, h, n, 1.f, 1.f, 0.f, 0.f, 0.f, 0.f, 0.f, 0.f, 0.f, 0.f);
    gemm_bf16<4, 4, true><<<g816, blk, 0, stream>>>(
        tb16, MbT, (float*)d_out, nullptr, nullptr, nullptr, nullptr, tf, Ff, nu16,
        n, h, h, 1.f, 1.f, 1.f, 0.f, 0.f, 0.f, 0.f, 0.f, 0.f, 0.f);
}

// Round 8
// 472.095 us; speedup vs baseline: 2.0815x; 2.0815x over previous
//
#include <hip/hip_runtime.h>

typedef __attribute__((ext_vector_type(8))) short short8v;
typedef __attribute__((ext_vector_type(4))) float f32x4;

typedef const __attribute__((address_space(1))) void gvoid_t;
typedef __attribute__((address_space(3))) void svoid_t;

__device__ __forceinline__ unsigned short f2b(float f) {
    unsigned u = __float_as_uint(f);
    unsigned r = (u + 0x7fffu + ((u >> 16) & 1u)) >> 16;
    return (unsigned short)r;
}
__device__ __forceinline__ float b2f(unsigned short h) {
    return __uint_as_float((unsigned)h << 16);
}

// ---------------- elementwise / setup kernels ----------------

__global__ void k_build_A(const float* __restrict__ adj,
                          const float* __restrict__ alpha,
                          float* __restrict__ Xs, unsigned short* __restrict__ Xb,
                          int n, float scale)
{
    int j = blockIdx.x * 256 + threadIdx.x;
    int i = blockIdx.y;
    if (j >= n) return;
    size_t idx = (size_t)i * n + j;
    float s = 1.f / (1.f + expf(-alpha[i]));
    float v = scale * s * (adj[idx] - (i == j ? 1.f : 0.f));
    Xs[idx] = v;
    Xb[idx] = f2b(v);
}

__global__ void k_build_EW(const float* __restrict__ w,
                           const float* __restrict__ d,
                           unsigned short* __restrict__ Eb,
                           unsigned short* __restrict__ Edb,
                           float* __restrict__ Edf, int h)
{
    int j = blockIdx.x * 256 + threadIdx.x;
    int i = blockIdx.y;
    if (j >= h) return;
    size_t idx = (size_t)i * h + j;
    float e = w[idx] - (i == j ? 1.f : 0.f);
    float dc = fminf(fmaxf(d[j], 0.f), 1.f);
    Eb[idx] = f2b(e);
    float ed = e * dc;
    Edb[idx] = f2b(ed);
    Edf[idx] = ed;
}

__global__ void k_build_R(const float* __restrict__ Ed,
                          const float* __restrict__ d,
                          float* __restrict__ R, int h, float dt)
{
    __shared__ float tile[32][33];
    int bx = blockIdx.x * 32, by = blockIdx.y * 32;
    int tx = threadIdx.x, ty = threadIdx.y;
    #pragma unroll
    for (int r = 0; r < 32; r += 8)
        tile[ty + r][tx] = Ed[(size_t)(bx + ty + r) * h + by + tx];
    __syncthreads();
    #pragma unroll
    for (int r = 0; r < 32; r += 8) {
        int i = by + ty + r, j = bx + tx;
        float v = Ed[(size_t)i * h + j] + tile[tx][ty + r];
        if (i == j) v += fminf(fmaxf(d[i], 0.f), 1.f) - 1.f;
        R[(size_t)i * h + j] = dt * v;
    }
}

__global__ void k_tsplit(const float* __restrict__ in,
                         unsigned short* __restrict__ outT, int R, int C)
{
    __shared__ float tile[32][33];
    int bx = blockIdx.x * 32, by = blockIdx.y * 32;
    int tx = threadIdx.x, ty = threadIdx.y;
    #pragma unroll
    for (int r = 0; r < 32; r += 8)
        tile[ty + r][tx] = in[(size_t)(by + ty + r) * C + bx + tx];
    __syncthreads();
    #pragma unroll
    for (int r = 0; r < 32; r += 8)
        outT[(size_t)(bx + ty + r) * R + by + tx] = f2b(tile[tx][ty + r]);
}

// ------- bf16 MFMA GEMM: 64x64 tile, BK=64, 2-buffer counted-vmcnt pipeline ----
// acc = A @ B  (A: MxK bf16 row-major; BT: NxK bf16 row-major = B transposed)
// v  = alpha*acc + beta*D + g2*D2 + g3*b2f(Db) -> C (f32), Cb (bf16), CbT ([N][M] bf16)
// v2 = pa*acc + pb*D + pc*b2f(Db)              -> Cb2 (bf16)
// v3 = qa*acc + qb*D + qc*b2f(Db)              -> Cb3 (bf16)
// 256 threads = 4 waves (2x2), per-wave 32x32 (2x2 frags of 16x16x32).
// LDS 32 KB (2 buffers) -> 4 blocks/CU possible; coalesced staging: 8 lanes
// cover each 128B row (XOR-permuted within the row, rule #21 both-sides);
// ds_read slot = (hf*4+l4) ^ (row&7) -> conflict-free b128 (R5/R6-verified).
// Loop: {vmcnt(LPT); barrier; read+MFMA; barrier; stage(t+2)} -- counted,
// never 0 mid-loop. XCD row-stripe swizzle: XCD q owns gy/8 row-blocks,
// column-major within the stripe (B-tile reused rpx consecutive blocks).

template<int FM, int FN>
__global__ __launch_bounds__(256, 4)
void gemm_bf16(const unsigned short* __restrict__ A,
               const unsigned short* __restrict__ BT,
               float* __restrict__ C,
               unsigned short* __restrict__ Cb,
               unsigned short* __restrict__ Cb2,
               unsigned short* __restrict__ Cb3,
               unsigned short* __restrict__ CbT,
               const float* __restrict__ D,
               const float* __restrict__ D2,
               const unsigned short* __restrict__ Db,
               int M, int N, int K,
               float alpha, float beta, float g2, float g3,
               float pa, float pb, float pc,
               float qa, float qb, float qc)
{
    constexpr int BM = FM * 32, BN = FN * 32, BK = 64;
    constexpr int AIT = BM * BK / (8 * 256);   // 16B chunks per thread (A)
    constexpr int BIT = BN * BK / (8 * 256);
    constexpr int LPT = AIT + BIT;
    __shared__ unsigned short As[2][BM * BK];
    __shared__ unsigned short Bs[2][BN * BK];

    // XCD row-stripe swizzle (requires gridDim.y % 8 == 0)
    int bid = blockIdx.y * gridDim.x + blockIdx.x;
    int rpx = gridDim.y >> 3;
    int q = bid & 7, c = bid >> 3;
    int by = q * rpx + (c % rpx);
    int bx = c / rpx;

    const int tid  = threadIdx.x;
    const int lane = tid & 63;
    const int wave = tid >> 6;
    const int wr = wave >> 1, wc = wave & 1;   // 2 x 2 wave grid
    const int l16 = lane & 15, l4 = lane >> 4;
    const int brow = by * BM, bcol = bx * BN;

    f32x4 acc[FM][FN];
    #pragma unroll
    for (int m = 0; m < FM; ++m)
        #pragma unroll
        for (int j = 0; j < FN; ++j)
            acc[m][j] = (f32x4){0.f, 0.f, 0.f, 0.f};

    const unsigned short* Ab = A + (size_t)brow * K;
    const unsigned short* Bb = BT + (size_t)bcol * K;
    const int nt = K / BK;

    auto stage = [&](int b, int k0) {
        #pragma unroll
        for (int it = 0; it < AIT; ++it) {
            int cb = it * 256 + wave * 64;          // wave-uniform chunk base
            int ch = cb + lane;
            int r = ch >> 3, cc = ch & 7;
            int cs = cc ^ (r & 7);                  // inverse-swizzled source
            __builtin_amdgcn_global_load_lds(
                (gvoid_t*)(Ab + (size_t)r * K + k0 + cs * 8),
                (svoid_t*)(&As[b][cb * 8]), 16, 0, 0);
        }
        #pragma unroll
        for (int it = 0; it < BIT; ++it) {
            int cb = it * 256 + wave * 64;
            int ch = cb + lane;
            int r = ch >> 3, cc = ch & 7;
            int cs = cc ^ (r & 7);
            __builtin_amdgcn_global_load_lds(
                (gvoid_t*)(Bb + (size_t)r * K + k0 + cs * 8),
                (svoid_t*)(&Bs[b][cb * 8]), 16, 0, 0);
        }
    };

    stage(0, 0);
    stage(1, BK);

    for (int t = 0; t < nt; ++t) {
        const int cur = t & 1;
        if (t + 1 < nt) {
            asm volatile("s_waitcnt vmcnt(%0)" :: "i"(LPT) : "memory");
        } else {
            asm volatile("s_waitcnt vmcnt(0)" ::: "memory");
        }
        __builtin_amdgcn_s_barrier();
        asm volatile("" ::: "memory");
        __builtin_amdgcn_sched_barrier(0);

        short8v af[FM][2], bf[FN][2];
        #pragma unroll
        for (int m = 0; m < FM; ++m) {
            int r = wr * FM * 16 + m * 16 + l16;
            #pragma unroll
            for (int hf = 0; hf < 2; ++hf) {
                int cs = (hf * 4 + l4) ^ (r & 7);    // swizzled read
                af[m][hf] = *(const short8v*)&As[cur][r * BK + cs * 8];
            }
        }
        #pragma unroll
        for (int j = 0; j < FN; ++j) {
            int r = wc * FN * 16 + j * 16 + l16;
            #pragma unroll
            for (int hf = 0; hf < 2; ++hf) {
                int cs = (hf * 4 + l4) ^ (r & 7);
                bf[j][hf] = *(const short8v*)&Bs[cur][r * BK + cs * 8];
            }
        }
        __builtin_amdgcn_s_setprio(1);
        #pragma unroll
        for (int hf = 0; hf < 2; ++hf)
            #pragma unroll
            for (int m = 0; m < FM; ++m)
                #pragma unroll
                for (int j = 0; j < FN; ++j)
                    acc[m][j] = __builtin_amdgcn_mfma_f32_16x16x32_bf16(
                        af[m][hf], bf[j][hf], acc[m][j], 0, 0, 0);
        __builtin_amdgcn_s_setprio(0);
        __builtin_amdgcn_sched_barrier(0);
        __builtin_amdgcn_s_barrier();
        asm volatile("" ::: "memory");
        if (t + 2 < nt) stage(cur, (t + 2) * BK);   // reuse just-freed buffer
    }

    #pragma unroll
    for (int m = 0; m < FM; ++m) {
        #pragma unroll
        for (int j = 0; j < FN; ++j) {
            const int row0 = brow + wr * FM * 16 + m * 16 + l4 * 4;
            const int col  = bcol + wc * FN * 16 + j * 16 + l16;
            float vv[4];
            #pragma unroll
            for (int q2 = 0; q2 < 4; ++q2) {
                size_t idx = (size_t)(row0 + q2) * N + col;
                float a0 = acc[m][j][q2];
                float v = alpha * a0;
                float dv = 0.f, dbv = 0.f;
                if (D)  { dv = D[idx]; v = fmaf(beta, dv, v); }
                if (D2) v = fmaf(g2, D2[idx], v);
                if (Db) { dbv = b2f(Db[idx]); v = fmaf(g3, dbv, v); }
                vv[q2] = v;
                if (C)  C[idx] = v;
                if (Cb) Cb[idx] = f2b(v);
                if (Cb2) {
                    float v2 = pa * a0;
                    if (D)  v2 = fmaf(pb, dv, v2);
                    if (Db) v2 = fmaf(pc, dbv, v2);
                    Cb2[idx] = f2b(v2);
                }
                if (Cb3) {
                    float v3 = qa * a0;
                    if (D)  v3 = fmaf(qb, dv, v3);
                    if (Db) v3 = fmaf(qc, dbv, v3);
                    Cb3[idx] = f2b(v3);
                }
            }
            if (CbT) {
                ushort4 t4;
                t4.x = f2b(vv[0]); t4.y = f2b(vv[1]);
                t4.z = f2b(vv[2]); t4.w = f2b(vv[3]);
                *reinterpret_cast<ushort4*>(&CbT[(size_t)col * M + row0]) = t4;
            }
        }
    }
}

// ---------------- host orchestration ----------------

extern "C" void kernel_launch(void* const* d_in, const int* in_sizes, int n_in,
                              void* d_out, int out_size, void* d_ws, size_t ws_size,
                              hipStream_t stream)
{
    const float* x     = (const float*)d_in[0];   // [n, h]
    const float* x0    = (const float*)d_in[1];   // [n, h]
    const float* adj   = (const float*)d_in[2];   // [n, n]
    const float* alpha = (const float*)d_in[3];   // [n]
    const float* w     = (const float*)d_in[4];   // [h, h]
    const float* dvec  = (const float*)d_in[5];   // [h]

    const int n = in_sizes[3];      // 2048
    const int h = in_sizes[5];      // 1024
    const size_t MB = 1u << 20;
    char* ws = (char*)d_ws;

    typedef unsigned short u16;
    // ---- workspace (MiB offsets, phase-overlaid; peak 106 MiB) ----
    float* Xs    = (float*)(ws + 0 * MB);    // 16  phase A (dies after A2)
    float* tf    = (float*)(ws + 0 * MB);    // 8   scan
    float* za    = (float*)(ws + 8 * MB);    // 8   scan
    u16*   XAb   = (u16*)(ws + 16 * MB);     // 8   dies after A1
    u16*   Eb_   = (u16*)(ws + 16 * MB);     // 2   phase B
    u16*   Edb   = (u16*)(ws + 18 * MB);     // 2
    float* Edf   = (float*)(ws + 20 * MB);   // 4
    u16*   XAT   = (u16*)(ws + 24 * MB);     // 8   dies after A2
    float* R     = (float*)(ws + 24 * MB);   // 4   phase B
    float* XBf   = (float*)(ws + 28 * MB);   // 4
    u16*   T2b   = (u16*)(ws + 32 * MB);     // 8   dies after A2
    u16*   XBb   = (u16*)(ws + 32 * MB);     // 2   phase B
    u16*   XBT   = (u16*)(ws + 34 * MB);     // 2
    u16*   t2b   = (u16*)(ws + 36 * MB);     // 2
    u16*   t3b   = (u16*)(ws + 38 * MB);     // 2
    u16*   Mah   = (u16*)(ws + 40 * MB);     // 8   persists (single step)
    u16*   Pmb   = (u16*)(ws + 48 * MB);     // 8   dies after F
    u16*   tb16  = (u16*)(ws + 48 * MB);     // 4   scan
    u16*   zt    = (u16*)(ws + 52 * MB);     // 4   scan
    u16*   M2ah  = (u16*)(ws + 56 * MB);     // 8   persists (dbl steps)
    float* S3    = (float*)(ws + 64 * MB);   // 4   phase B
    u16*   x0T   = (u16*)(ws + 64 * MB);     // 4   phase C pre (S3 dead)
    u16*   MbT   = (u16*)(ws + 68 * MB);     // 2   persists
    u16*   Mbb   = (u16*)(ws + 70 * MB);     // 2   dies after B5
    u16*   FTb   = (u16*)(ws + 72 * MB);     // 4   dies after u-gemm
    u16*   M2bTb = (u16*)(ws + 76 * MB);     // 2   persists (dbl steps)
    float* Ff    = (float*)(ws + 78 * MB);   // 8   persists
    float* uf    = (float*)(ws + 86 * MB);   // 8   dies after F2
    u16*   ub    = (u16*)(ws + 94 * MB);     // 4   dies after F2
    float* F2f   = (float*)(ws + 98 * MB);   // 8   persists (dbl steps)

    const dim3 blk(256);
    const dim3 gNN(n / 64, n / 64);   // 32x32 = 1024 blocks (4/CU)
    const dim3 gHN(h / 64, n / 64);   // 16x32 = 512 blocks  (2/CU)
    const dim3 gHH(h / 64, h / 64);   // 16x16 = 256 blocks  (1/CU)
    const float dt = 0.1f;
    const u16* nu16 = nullptr;
    const float* nf32 = nullptr;

    // ===== Phase A: Mah=bf16(e^X-I), Pmb=bf16(phi1-I), M2ah=bf16(e^{2X}-I) =====
    k_build_A<<<dim3(n / 256, n), blk, 0, stream>>>(adj, alpha, Xs, XAb, n, 0.5f * dt);
    k_tsplit<<<dim3(n / 32, n / 32), dim3(32, 8), 0, stream>>>(Xs, XAT, n, n);
    // A1: T2b = bf16(X^2)
    gemm_bf16<2, 2><<<gNN, blk, 0, stream>>>(
        XAb, XAT, nullptr, T2b, nullptr, nullptr, nullptr, nf32, nf32, nu16,
        n, n, n, 1.f, 0.f, 0.f, 0.f, 0.f, 0.f, 0.f, 0.f, 0.f, 0.f);
    // A2: acc = X^2@X = X^3
    //   Ma  = X + X^2/2 + X^3/6        -> Mah
    //   Pm  = X/2 + X^2/6 + X^3/24     -> Pmb
    //   M2a = 2X + 2X^2 + (4/3)X^3     -> M2ah
    gemm_bf16<2, 2><<<gNN, blk, 0, stream>>>(
        T2b, XAT, nullptr, Mah, Pmb, M2ah, nullptr, Xs, nf32, T2b,
        n, n, n, 1.f / 6.f, 1.f, 0.f, 0.5f,
        1.f / 24.f, 0.5f, 1.f / 6.f, 4.f / 3.f, 2.f, 2.f);

    // ===== Phase B: Mb = e^{dtB}-I (order 4), M2bT = (Mb^2+2Mb)^T =====
    k_build_EW<<<dim3(h / 256, h), blk, 0, stream>>>(w, dvec, Eb_, Edb, Edf, h);
    k_build_R<<<dim3(h / 32, h / 32), dim3(32, 8), 0, stream>>>(Edf, dvec, R, h, dt);
    // B1: XB = dt*(Ed @ E^T) + R
    gemm_bf16<2, 2><<<gHH, blk, 0, stream>>>(
        Edb, Eb_, XBf, XBb, nullptr, nullptr, XBT, R, nf32, nu16,
        h, h, h, dt, 1.f, 0.f, 0.f, 0.f, 0.f, 0.f, 0.f, 0.f, 0.f);
    // B2: t2b = bf16(XB^2/2)
    gemm_bf16<2, 2><<<gHH, blk, 0, stream>>>(
        XBb, XBT, nullptr, t2b, nullptr, nullptr, nullptr, nf32, nf32, nu16,
        h, h, h, 0.5f, 0.f, 0.f, 0.f, 0.f, 0.f, 0.f, 0.f, 0.f, 0.f);
    // B3: acc = t2@XB = XB^3/2 ; S3 = acc/3 + XBf + t2 ; t3b = bf16(acc/3)
    gemm_bf16<2, 2><<<gHH, blk, 0, stream>>>(
        t2b, XBT, S3, nullptr, t3b, nullptr, nullptr, XBf, nf32, t2b,
        h, h, h, 1.f / 3.f, 1.f, 0.f, 1.f, 1.f / 3.f, 0.f, 0.f, 0.f, 0.f, 0.f);
    // B4: Mb = acc/4 + S3 -> MbT (CbT) + Mbb (Cb)
    gemm_bf16<2, 2><<<gHH, blk, 0, stream>>>(
        t3b, XBT, nullptr, Mbb, nullptr, nullptr, MbT, S3, nf32, nu16,
        h, h, h, 0.25f, 1.f, 0.f, 0.f, 0.f, 0.f, 0.f, 0.f, 0.f, 0.f);
    // B5: M2b^T = (Mb^T)^2 + 2 Mb^T  (A=MbT, BT=Mbb)
    gemm_bf16<2, 2><<<gHH, blk, 0, stream>>>(
        MbT, Mbb, nullptr, M2bTb, nullptr, nullptr, nullptr, nf32, nf32, MbT,
        h, h, h, 1.f, 0.f, 0.f, 2.f, 0.f, 0.f, 0.f, 0.f, 0.f, 0.f);

    // ===== Phase C: forcing chain =====
    k_tsplit<<<dim3(h / 32, n / 32), dim3(32, 8), 0, stream>>>(x0, x0T, n, h);
    // F = dt*(Pm@x0) + dt*x0 -> Ff + FTb
    gemm_bf16<2, 2><<<gHN, blk, 0, stream>>>(
        Pmb, x0T, Ff, nullptr, nullptr, nullptr, FTb, x0, nf32, nu16,
        n, h, n, dt, dt, 0.f, 0.f, 0.f, 0.f, 0.f, 0.f, 0.f, 0.f);
    // u = Ma@F + F -> uf + ub
    gemm_bf16<2, 2><<<gHN, blk, 0, stream>>>(
        Mah, FTb, uf, ub, nullptr, nullptr, nullptr, Ff, nf32, nu16,
        n, h, n, 1.f, 1.f, 0.f, 0.f, 0.f, 0.f, 0.f, 0.f, 0.f, 0.f);
    // F2 = u@Mb + u + F
    gemm_bf16<2, 2><<<gHN, blk, 0, stream>>>(
        ub, MbT, F2f, nullptr, nullptr, nullptr, nullptr, uf, Ff, nu16,
        n, h, h, 1.f, 1.f, 1.f, 0.f, 0.f, 0.f, 0.f, 0.f, 0.f, 0.f);

    // ===== scan: 4 double-steps + 1 single step (total 9 = int(1.0//0.1)) =====
    k_tsplit<<<dim3(h / 32, n / 32), dim3(32, 8), 0, stream>>>(x, zt, n, h);
    const float* zf = x;
    for (int s = 0; s < 4; ++s) {
        // G1: tf = M2a@z + z ; tb16 = bf16(tf)
        gemm_bf16<2, 2><<<gHN, blk, 0, stream>>>(
            M2ah, zt, tf, tb16, nullptr, nullptr, nullptr, zf, nf32, nu16,
            n, h, n, 1.f, 1.f, 0.f, 0.f, 0.f, 0.f, 0.f, 0.f, 0.f, 0.f);
        // G2: z'' = t@M2b + t + F2 -> za (f32) + zt (bf16 transposed)
        gemm_bf16<2, 2><<<gHN, blk, 0, stream>>>(
            tb16, M2bTb, za, nullptr, nullptr, nullptr, zt, tf, F2f, nu16,
            n, h, h, 1.f, 1.f, 1.f, 0.f, 0.f, 0.f, 0.f, 0.f, 0.f, 0.f);
        zf = za;
    }
    // single step: tf = Ma@z + z ; out = t@Mb + t + F
    gemm_bf16<2, 2><<<gHN, blk, 0, stream>>>(
        Mah, zt, tf, tb16, nullptr, nullptr, nullptr, za, nf32, nu16,
        n, h, n, 1.f, 1.f, 0.f, 0.f, 0.f, 0.f, 0.f, 0.f, 0.f, 0.f);
    gemm_bf16<2, 2><<<gHN, blk, 0, stream>>>(
        tb16, MbT, (float*)d_out, nullptr, nullptr, nullptr, nullptr, tf, Ff, nu16,
        n, h, h, 1.f, 1.f, 1.f, 0.f, 0.f, 0.f, 0.f, 0.f, 0.f, 0.f);
}